// Round 1
// baseline (264.839 us; speedup 1.0000x reference)
//
#include <hip/hip_runtime.h>

// Sizes (fixed by the reference)
#define NB_B 16
#define NN   1024
#define NW   32
#define NCS  12
#define NH1  40
#define NH2  10

// Workspace layout (float offsets). Scratch region is time-shared:
//   P_feat (3*1024*16*40) -> P2 (8*1024*160) -> P3 (8*1024*16)
#define OFF_DIS  0
#define OFF_G0   1024
#define OFF_X1   (OFF_G0 + NN*NB_B*NH1)
#define OFF_G1   (OFF_X1 + NN*NB_B*NH1)
#define OFF_G2   (OFF_G1 + NN*NB_B*NH2)
#define OFF_SCR  (OFF_G2 + NN*NB_B)

// ---------------------------------------------------------------------------
// dis[i] = rsqrt(max(1, 1 + sum_j A0[i,j]))   (A batch-tiled: use batch 0)
__global__ __launch_bounds__(256) void k_dis(const float* __restrict__ A0,
                                             float* __restrict__ dis) {
    int i = blockIdx.x;
    const float* row = A0 + (size_t)i * NN;
    float s = 0.f;
    for (int j = threadIdx.x; j < NN; j += 256) s += row[j];
#pragma unroll
    for (int off = 32; off > 0; off >>= 1) s += __shfl_down(s, off);
    __shared__ float red[4];
    int lane = threadIdx.x & 63, wv = threadIdx.x >> 6;
    if (lane == 0) red[wv] = s;
    __syncthreads();
    if (threadIdx.x == 0) {
        float deg = 1.f + red[0] + red[1] + red[2] + red[3];
        dis[i] = rsqrtf(fmaxf(deg, 1.f));
    }
}

// ---------------------------------------------------------------------------
// Fused conv-branch + relu + (xconv @ Wg1) partial.  One block: (node-tile of
// 256, batch b, branch br).  Writes P[br][node][b][h]  (pre-dis, pre-bias).
template <int KSZ, int LK, int DBASE, int BR>
__device__ __forceinline__ void feat_body(const float* __restrict__ x,
                                          const float* __restrict__ Wc,
                                          const float* __restrict__ bc,
                                          const float* __restrict__ Wg1,
                                          float* __restrict__ P,
                                          float (*xs)[256], float (*xc)[256]) {
    int tid = threadIdx.x;
    int n0 = blockIdx.x * 256;
    int b  = blockIdx.y;
    for (int idx = tid; idx < NW * 256; idx += 256) {
        int w = idx >> 8, j = idx & 255;
        xs[w][j] = x[((size_t)b * NW + w) * NN + n0 + j];
    }
    __syncthreads();
    int hg = tid & 3, ng = tid >> 2;
    int h0 = hg * 10;
    float acc[4][10];
#pragma unroll
    for (int a = 0; a < 4; ++a)
#pragma unroll
        for (int u = 0; u < 10; ++u) acc[a][u] = 0.f;

    for (int cs = 0; cs < NCS; ++cs) {
        if (cs) __syncthreads();
        float wk[KSZ];
#pragma unroll
        for (int t = 0; t < KSZ; ++t) wk[t] = Wc[cs * KSZ + t];
        float bb = bc[cs];
        for (int l = 0; l < LK; ++l) {
            float s = bb;
#pragma unroll
            for (int t = 0; t < KSZ; ++t) s += xs[l + t][tid] * wk[t];
            xc[l][tid] = fmaxf(s, 0.f);
        }
        __syncthreads();
        const float* wrow = Wg1 + (size_t)(DBASE + cs * LK) * NH1 + h0;
        for (int l = 0; l < LK; ++l) {
            float4 xv = *(const float4*)&xc[l][ng * 4];
            const float* wr = wrow + l * NH1;
#pragma unroll
            for (int u = 0; u < 10; ++u) {
                float wv = wr[u];
                acc[0][u] = fmaf(xv.x, wv, acc[0][u]);
                acc[1][u] = fmaf(xv.y, wv, acc[1][u]);
                acc[2][u] = fmaf(xv.z, wv, acc[2][u]);
                acc[3][u] = fmaf(xv.w, wv, acc[3][u]);
            }
        }
    }
#pragma unroll
    for (int nn = 0; nn < 4; ++nn) {
        int n = n0 + ng * 4 + nn;
        float* dst = P + (((size_t)BR * NN + n) * NB_B + b) * NH1 + h0;
#pragma unroll
        for (int u = 0; u < 10; ++u) dst[u] = acc[nn][u];
    }
}

__global__ __launch_bounds__(256) void k_feat(
    const float* __restrict__ x, const float* __restrict__ W1,
    const float* __restrict__ b1, const float* __restrict__ W2,
    const float* __restrict__ b2, const float* __restrict__ W3,
    const float* __restrict__ b3, const float* __restrict__ Wg1,
    float* __restrict__ P) {
    __shared__ float xs[NW][256];
    __shared__ float xc[30][256];
    int br = blockIdx.z;
    if (br == 0)      feat_body<3, 30, 0,   0>(x, W1, b1, Wg1, P, xs, xc);
    else if (br == 1) feat_body<5, 28, 360, 1>(x, W2, b2, Wg1, P, xs, xc);
    else              feat_body<7, 26, 696, 2>(x, W3, b3, Wg1, P, xs, xc);
}

// ---------------------------------------------------------------------------
// G0[n][b][h] = dis[n] * (P0+P1+P2)[n][b][h]
__global__ __launch_bounds__(256) void k_combine(const float* __restrict__ P,
                                                 const float* __restrict__ dis,
                                                 float* __restrict__ G0) {
    int t = blockIdx.x * 256 + threadIdx.x;  // < 163840 float4s
    int n = t / 160;
    const float4* p = (const float4*)P;
    float4 a = p[t];
    float4 b = p[t + NN * 160];
    float4 c = p[t + 2 * NN * 160];
    float d = dis[n];
    float4 o;
    o.x = d * (a.x + b.x + c.x);
    o.y = d * (a.y + b.y + c.y);
    o.z = d * (a.z + b.z + c.z);
    o.w = d * (a.w + b.w + c.w);
    ((float4*)G0)[t] = o;
}

// ---------------------------------------------------------------------------
// X1[i][bh] = relu(dis[i]*(sum_j A0[i,j]*G0[j][bh] + G0[i][bh]) + bg1[h])
// GEMM M=1024, N=640, K=1024, tile 64x64, micro 4x4.
__global__ __launch_bounds__(256) void k_prop1(const float* __restrict__ A0,
                                               const float* __restrict__ G0,
                                               const float* __restrict__ dis,
                                               const float* __restrict__ bg1,
                                               float* __restrict__ X1) {
    __shared__ float As[32][68];  // As[k][i] (transposed)
    __shared__ float Bs[32][68];  // Bs[k][n]
    int tid = threadIdx.x;
    int n0 = blockIdx.x * 64;
    int i0 = blockIdx.y * 64;
    int tx = tid & 15, ty = tid >> 4;
    float acc[4][4] = {};
    for (int kc = 0; kc < NN; kc += 32) {
#pragma unroll
        for (int v = 0; v < 2; ++v) {
            int fid = tid + v * 256;
            int r = fid >> 3, c4 = (fid & 7) * 4;
            float4 a = *(const float4*)&A0[(size_t)(i0 + r) * NN + kc + c4];
            As[c4 + 0][r] = a.x; As[c4 + 1][r] = a.y;
            As[c4 + 2][r] = a.z; As[c4 + 3][r] = a.w;
            int r2 = fid >> 4, c42 = (fid & 15) * 4;
            *(float4*)&Bs[r2][c42] =
                *(const float4*)&G0[(size_t)(kc + r2) * 640 + n0 + c42];
        }
        __syncthreads();
#pragma unroll
        for (int kk = 0; kk < 32; ++kk) {
            float4 av = *(const float4*)&As[kk][ty * 4];
            float4 bv = *(const float4*)&Bs[kk][tx * 4];
            acc[0][0] = fmaf(av.x, bv.x, acc[0][0]);
            acc[0][1] = fmaf(av.x, bv.y, acc[0][1]);
            acc[0][2] = fmaf(av.x, bv.z, acc[0][2]);
            acc[0][3] = fmaf(av.x, bv.w, acc[0][3]);
            acc[1][0] = fmaf(av.y, bv.x, acc[1][0]);
            acc[1][1] = fmaf(av.y, bv.y, acc[1][1]);
            acc[1][2] = fmaf(av.y, bv.z, acc[1][2]);
            acc[1][3] = fmaf(av.y, bv.w, acc[1][3]);
            acc[2][0] = fmaf(av.z, bv.x, acc[2][0]);
            acc[2][1] = fmaf(av.z, bv.y, acc[2][1]);
            acc[2][2] = fmaf(av.z, bv.z, acc[2][2]);
            acc[2][3] = fmaf(av.z, bv.w, acc[2][3]);
            acc[3][0] = fmaf(av.w, bv.x, acc[3][0]);
            acc[3][1] = fmaf(av.w, bv.y, acc[3][1]);
            acc[3][2] = fmaf(av.w, bv.z, acc[3][2]);
            acc[3][3] = fmaf(av.w, bv.w, acc[3][3]);
        }
        __syncthreads();
    }
    int col = n0 + tx * 4;
    int h0 = col % 40;
    float4 bv = *(const float4*)&bg1[h0];
#pragma unroll
    for (int iy = 0; iy < 4; ++iy) {
        int i = i0 + ty * 4 + iy;
        float di = dis[i];
        float4 g = *(const float4*)&G0[(size_t)i * 640 + col];
        float4 o;
        o.x = fmaxf(di * (acc[iy][0] + g.x) + bv.x, 0.f);
        o.y = fmaxf(di * (acc[iy][1] + g.y) + bv.y, 0.f);
        o.z = fmaxf(di * (acc[iy][2] + g.z) + bv.z, 0.f);
        o.w = fmaxf(di * (acc[iy][3] + g.w) + bv.w, 0.f);
        *(float4*)&X1[(size_t)i * 640 + col] = o;
    }
}

// ---------------------------------------------------------------------------
// G1[i][b][m] = dis[i] * sum_h X1[i][b][h] * Wg2[h][m]
__global__ __launch_bounds__(256) void k_x1w2(const float* __restrict__ X1,
                                              const float* __restrict__ Wg2,
                                              const float* __restrict__ dis,
                                              float* __restrict__ G1) {
    __shared__ float w2[NH1 * NH2];
    int tid = threadIdx.x;
    for (int idx = tid; idx < NH1 * NH2; idx += 256) w2[idx] = Wg2[idx];
    __syncthreads();
    int t = blockIdx.x * 256 + tid;  // < 16384
    int i = t >> 4, b = t & 15;
    const float* xr = X1 + (size_t)i * 640 + b * 40;
    float di = dis[i];
    float o[10];
#pragma unroll
    for (int m = 0; m < 10; ++m) o[m] = 0.f;
#pragma unroll
    for (int h4 = 0; h4 < 10; ++h4) {
        float4 xv = *(const float4*)&xr[h4 * 4];
#pragma unroll
        for (int m = 0; m < 10; ++m) {
            o[m] = fmaf(xv.x, w2[(h4 * 4 + 0) * 10 + m], o[m]);
            o[m] = fmaf(xv.y, w2[(h4 * 4 + 1) * 10 + m], o[m]);
            o[m] = fmaf(xv.z, w2[(h4 * 4 + 2) * 10 + m], o[m]);
            o[m] = fmaf(xv.w, w2[(h4 * 4 + 3) * 10 + m], o[m]);
        }
    }
    float* dst = G1 + (size_t)i * 160 + b * 10;
#pragma unroll
    for (int m = 0; m < 10; ++m) dst[m] = di * o[m];
}

// ---------------------------------------------------------------------------
// P2[kc][i][c] = sum_{j in chunk kc} A0[i,j] * G1[j][c]   (c = b*10+m, 160)
// K-split x8 for parallelism; tile 64i x 160c, micro 4x10.
__global__ __launch_bounds__(256) void k_prop2(const float* __restrict__ A0,
                                               const float* __restrict__ G1,
                                               float* __restrict__ P2) {
    __shared__ float As[32][68];
    __shared__ float Gs[32][164];
    int tid = threadIdx.x;
    int kb = blockIdx.x * 128;
    int i0 = blockIdx.y * 64;
    int cg = tid & 15, ig = tid >> 4;
    float acc[4][10] = {};
    for (int kc = 0; kc < 128; kc += 32) {
#pragma unroll
        for (int v = 0; v < 2; ++v) {
            int fid = tid + v * 256;
            int r = fid >> 3, c4 = (fid & 7) * 4;
            float4 a = *(const float4*)&A0[(size_t)(i0 + r) * NN + kb + kc + c4];
            As[c4 + 0][r] = a.x; As[c4 + 1][r] = a.y;
            As[c4 + 2][r] = a.z; As[c4 + 3][r] = a.w;
        }
#pragma unroll
        for (int v = 0; v < 5; ++v) {
            int fid = tid + v * 256;  // < 1280
            int r = fid / 40, c4 = (fid % 40) * 4;
            *(float4*)&Gs[r][c4] =
                *(const float4*)&G1[(size_t)(kb + kc + r) * 160 + c4];
        }
        __syncthreads();
#pragma unroll
        for (int kk = 0; kk < 32; ++kk) {
            float4 av = *(const float4*)&As[kk][ig * 4];
#pragma unroll
            for (int u = 0; u < 10; ++u) {
                float g = Gs[kk][cg + 16 * u];
                acc[0][u] = fmaf(av.x, g, acc[0][u]);
                acc[1][u] = fmaf(av.y, g, acc[1][u]);
                acc[2][u] = fmaf(av.z, g, acc[2][u]);
                acc[3][u] = fmaf(av.w, g, acc[3][u]);
            }
        }
        __syncthreads();
    }
#pragma unroll
    for (int iy = 0; iy < 4; ++iy) {
        float* dst = P2 + ((size_t)blockIdx.x * NN + i0 + ig * 4 + iy) * 160;
#pragma unroll
        for (int u = 0; u < 10; ++u) dst[cg + 16 * u] = acc[iy][u];
    }
}

// ---------------------------------------------------------------------------
// Reduce P2, finish layer 2, fuse X2 @ Wg3:  G2[i][b] = dis[i]*sum_m X2*Wg3
__global__ __launch_bounds__(256) void k_red2(const float* __restrict__ P2,
                                              const float* __restrict__ G1,
                                              const float* __restrict__ dis,
                                              const float* __restrict__ bg2,
                                              const float* __restrict__ Wg3,
                                              float* __restrict__ G2) {
    int t = blockIdx.x * 256 + threadIdx.x;  // < 16384
    int i = t >> 4, b = t & 15;
    float s[10];
#pragma unroll
    for (int m = 0; m < 10; ++m) s[m] = G1[(size_t)i * 160 + b * 10 + m];
    for (int kc = 0; kc < 8; ++kc) {
        const float* p = P2 + (size_t)kc * NN * 160 + (size_t)i * 160 + b * 10;
#pragma unroll
        for (int m = 0; m < 10; ++m) s[m] += p[m];
    }
    float di = dis[i];
    float g2 = 0.f;
#pragma unroll
    for (int m = 0; m < 10; ++m) {
        float x2 = fmaxf(di * s[m] + bg2[m], 0.f);
        g2 = fmaf(x2, Wg3[m], g2);
    }
    G2[(size_t)i * 16 + b] = di * g2;
}

// ---------------------------------------------------------------------------
// P3[kc][i][b] = sum_{j in chunk} A0[i,j]*G2[j][b];  tile 128i x 16b, K-split x8
__global__ __launch_bounds__(256) void k_prop3(const float* __restrict__ A0,
                                               const float* __restrict__ G2,
                                               float* __restrict__ P3) {
    __shared__ float As[32][132];
    __shared__ float G2s[128][16];
    int tid = threadIdx.x;
    int kb = blockIdx.x * 128;
    int i0 = blockIdx.y * 128;
#pragma unroll
    for (int v = 0; v < 2; ++v) {
        int fid = tid + v * 256;  // < 512
        int r = fid >> 2, c4 = (fid & 3) * 4;
        *(float4*)&G2s[r][c4] = *(const float4*)&G2[(size_t)(kb + r) * 16 + c4];
    }
    int il = tid >> 1, c0 = (tid & 1) * 8;
    float acc[8] = {};
    for (int jc = 0; jc < 128; jc += 32) {
#pragma unroll
        for (int v = 0; v < 4; ++v) {
            int fid = tid + v * 256;  // < 1024
            int r = fid >> 3, c4 = (fid & 7) * 4;
            float4 a = *(const float4*)&A0[(size_t)(i0 + r) * NN + kb + jc + c4];
            As[c4 + 0][r] = a.x; As[c4 + 1][r] = a.y;
            As[c4 + 2][r] = a.z; As[c4 + 3][r] = a.w;
        }
        __syncthreads();
#pragma unroll
        for (int kk = 0; kk < 32; ++kk) {
            float a = As[kk][il];
            float4 g0 = *(const float4*)&G2s[jc + kk][c0];
            float4 g1 = *(const float4*)&G2s[jc + kk][c0 + 4];
            acc[0] = fmaf(a, g0.x, acc[0]);
            acc[1] = fmaf(a, g0.y, acc[1]);
            acc[2] = fmaf(a, g0.z, acc[2]);
            acc[3] = fmaf(a, g0.w, acc[3]);
            acc[4] = fmaf(a, g1.x, acc[4]);
            acc[5] = fmaf(a, g1.y, acc[5]);
            acc[6] = fmaf(a, g1.z, acc[6]);
            acc[7] = fmaf(a, g1.w, acc[7]);
        }
        __syncthreads();
    }
    float* dst = P3 + (size_t)blockIdx.x * NN * 16 + (size_t)(i0 + il) * 16 + c0;
#pragma unroll
    for (int u = 0; u < 8; ++u) dst[u] = acc[u];
}

// ---------------------------------------------------------------------------
// out[b][i] = dis[i]*(sum_kc P3 + G2[i][b]) + bg3
__global__ __launch_bounds__(256) void k_red3(const float* __restrict__ P3,
                                              const float* __restrict__ G2,
                                              const float* __restrict__ dis,
                                              const float* __restrict__ bg3,
                                              float* __restrict__ out) {
    int t = blockIdx.x * 256 + threadIdx.x;  // < 16384
    int i = t >> 4, b = t & 15;
    float s = G2[(size_t)i * 16 + b];
#pragma unroll
    for (int kc = 0; kc < 8; ++kc) s += P3[(size_t)kc * NN * 16 + i * 16 + b];
    out[(size_t)b * NN + i] = dis[i] * s + bg3[0];
}

// ---------------------------------------------------------------------------
extern "C" void kernel_launch(void* const* d_in, const int* in_sizes, int n_in,
                              void* d_out, int out_size, void* d_ws,
                              size_t ws_size, hipStream_t stream) {
    (void)in_sizes; (void)n_in; (void)out_size; (void)ws_size;
    const float* x   = (const float*)d_in[0];
    const float* A   = (const float*)d_in[1];  // batch-tiled; use batch 0 only
    const float* W1  = (const float*)d_in[2];
    const float* b1  = (const float*)d_in[3];
    const float* W2  = (const float*)d_in[4];
    const float* b2  = (const float*)d_in[5];
    const float* W3  = (const float*)d_in[6];
    const float* b3  = (const float*)d_in[7];
    const float* Wg1 = (const float*)d_in[8];
    const float* bg1 = (const float*)d_in[9];
    const float* Wg2 = (const float*)d_in[10];
    const float* bg2 = (const float*)d_in[11];
    const float* Wg3 = (const float*)d_in[12];
    const float* bg3 = (const float*)d_in[13];
    float* ws  = (float*)d_ws;
    float* dis = ws + OFF_DIS;
    float* G0  = ws + OFF_G0;
    float* X1  = ws + OFF_X1;
    float* G1  = ws + OFF_G1;
    float* G2  = ws + OFF_G2;
    float* SCR = ws + OFF_SCR;
    float* out = (float*)d_out;

    k_dis<<<NN, 256, 0, stream>>>(A, dis);
    k_feat<<<dim3(4, 16, 3), 256, 0, stream>>>(x, W1, b1, W2, b2, W3, b3, Wg1, SCR);
    k_combine<<<640, 256, 0, stream>>>(SCR, dis, G0);
    k_prop1<<<dim3(10, 16), 256, 0, stream>>>(A, G0, dis, bg1, X1);
    k_x1w2<<<64, 256, 0, stream>>>(X1, Wg2, dis, G1);
    k_prop2<<<dim3(8, 16), 256, 0, stream>>>(A, G1, SCR);
    k_red2<<<64, 256, 0, stream>>>(SCR, G1, dis, bg2, Wg3, G2);
    k_prop3<<<dim3(8, 8), 256, 0, stream>>>(A, G2, SCR);
    k_red3<<<64, 256, 0, stream>>>(SCR, G2, dis, bg3, out);
}

// Round 4
// 219.910 us; speedup vs baseline: 1.2043x; 1.2043x over previous
//
#include <hip/hip_runtime.h>

// Sizes (fixed by the reference)
#define NB_B 16
#define NN   1024
#define NW   32
#define NCS  12
#define NH1  40
#define NH2  10

// Workspace layout (float offsets). Scratch region is time-shared:
//   Pf (3*16*40*1024) -> P1b (2*1024*640) -> P2 (8*1024*160) -> P3 (8*1024*16)
#define OFF_DIS  0
#define OFF_G0T  1024
#define OFF_X1   (OFF_G0T + NN*NB_B*NH1)
#define OFF_G1   (OFF_X1 + NN*NB_B*NH1)
#define OFF_G2   (OFF_G1 + NN*NB_B*NH2)
#define OFF_SCR  (OFF_G2 + NN*NB_B)

// ---------------------------------------------------------------------------
// dis[i] = rsqrt(max(1, 1 + sum_j A0[i,j]))   (A batch-tiled: use batch 0)
__global__ __launch_bounds__(256) void k_dis(const float* __restrict__ A0,
                                             float* __restrict__ dis) {
    int i = blockIdx.x;
    const float* row = A0 + (size_t)i * NN;
    float s = 0.f;
    for (int j = threadIdx.x; j < NN; j += 256) s += row[j];
#pragma unroll
    for (int off = 32; off > 0; off >>= 1) s += __shfl_down(s, off);
    __shared__ float red[4];
    int lane = threadIdx.x & 63, wv = threadIdx.x >> 6;
    if (lane == 0) red[wv] = s;
    __syncthreads();
    if (threadIdx.x == 0) {
        float deg = 1.f + red[0] + red[1] + red[2] + red[3];
        dis[i] = rsqrtf(fmaxf(deg, 1.f));
    }
}

// ---------------------------------------------------------------------------
// Fused conv-branch + relu + (xconv @ Wg1) partial, all-register version.
// Block = 64 nodes x 4 h-quarter waves; grid (16 ntiles, 16 b, 3 br).
// Thread: conv values in regs, Wg1 via wave-uniform scalar loads.
// Writes Pf[br][b][h][n]  (pre-dis, pre-bias), coalesced along n.
template <int KSZ, int LK, int DBASE, int BR>
__device__ __forceinline__ void feat_body(const float* __restrict__ x,
                                          const float* __restrict__ Wc,
                                          const float* __restrict__ bc,
                                          const float* __restrict__ Wg1,
                                          float* __restrict__ Pf) {
    int lane = threadIdx.x & 63;
    int hq = __builtin_amdgcn_readfirstlane(threadIdx.x >> 6);  // wave-uniform
    int n = blockIdx.x * 64 + lane;
    int b = blockIdx.y;

    float xs[NW];
#pragma unroll
    for (int w = 0; w < NW; ++w) xs[w] = x[((size_t)b * NW + w) * NN + n];

    float acc[10];
#pragma unroll
    for (int u = 0; u < 10; ++u) acc[u] = 0.f;

    const float* wg = Wg1 + (size_t)DBASE * NH1 + hq * 10;
    for (int cs = 0; cs < NCS; ++cs) {
        float wk[KSZ];
#pragma unroll
        for (int t = 0; t < KSZ; ++t) wk[t] = Wc[cs * KSZ + t];
        float bb = bc[cs];
#pragma unroll
        for (int l = 0; l < LK; ++l) {
            float s = bb;
#pragma unroll
            for (int t = 0; t < KSZ; ++t) s = fmaf(xs[l + t], wk[t], s);
            s = fmaxf(s, 0.f);
            const float* wr = wg + (size_t)(cs * LK + l) * NH1;  // uniform
#pragma unroll
            for (int u = 0; u < 10; ++u) acc[u] = fmaf(s, wr[u], acc[u]);
        }
    }
    float* dst = Pf + (((size_t)BR * NB_B + b) * NH1 + hq * 10) * NN + n;
#pragma unroll
    for (int u = 0; u < 10; ++u) dst[(size_t)u * NN] = acc[u];
}

__global__ __launch_bounds__(256) void k_feat(
    const float* __restrict__ x, const float* __restrict__ W1,
    const float* __restrict__ b1, const float* __restrict__ W2,
    const float* __restrict__ b2, const float* __restrict__ W3,
    const float* __restrict__ b3, const float* __restrict__ Wg1,
    float* __restrict__ Pf) {
    int br = blockIdx.z;
    if (br == 0)      feat_body<3, 30, 0,   0>(x, W1, b1, Wg1, Pf);
    else if (br == 1) feat_body<5, 28, 360, 1>(x, W2, b2, Wg1, Pf);
    else              feat_body<7, 26, 696, 2>(x, W3, b3, Wg1, Pf);
}

// ---------------------------------------------------------------------------
// G0T[c][n] = dis[n] * sum_br Pf[br][b][h][n]   (c = b*40+h)
// One block per c-row; fully coalesced both sides.
__global__ __launch_bounds__(256) void k_combine(const float* __restrict__ Pf,
                                                 const float* __restrict__ dis,
                                                 float* __restrict__ G0T) {
    int c = blockIdx.x;  // < 640
    const float* p = Pf + (size_t)c * NN;
    float* dst = G0T + (size_t)c * NN;
#pragma unroll
    for (int k = 0; k < 4; ++k) {
        int n = k * 256 + threadIdx.x;
        float v = p[n] + p[(size_t)NB_B * NH1 * NN + n] +
                  p[(size_t)2 * NB_B * NH1 * NN + n];
        dst[n] = dis[n] * v;
    }
}

// ---------------------------------------------------------------------------
// K-split GEMM: P1[z][i][c] = sum_{j in Kz} A0[i,j]*G0T[c][j]
// M=1024(i), N=640(c), K-range per z; tile 64x64, micro 4x4.
// z=0 -> P1a (X1 buffer, finished in-place later); z=1,2 -> P1b.
__global__ __launch_bounds__(256) void k_prop1s(const float* __restrict__ A0,
                                                const float* __restrict__ G0T,
                                                float* __restrict__ P1a,
                                                float* __restrict__ P1b) {
    __shared__ float As[32][68];  // As[k][i] (transposed)
    __shared__ float Bs[32][68];  // Bs[k][c]
    int tid = threadIdx.x;
    int n0 = blockIdx.x * 64;
    int i0 = blockIdx.y * 64;
    int z  = blockIdx.z;
    int kc0 = z * 352;
    int kc1 = (z == 2) ? NN : kc0 + 352;
    float* P = (z == 0) ? P1a : (P1b + (size_t)(z - 1) * NN * 640);
    int tx = tid & 15, ty = tid >> 4;
    float acc[4][4] = {};
    for (int kc = kc0; kc < kc1; kc += 32) {
#pragma unroll
        for (int v = 0; v < 2; ++v) {
            int fid = tid + v * 256;
            int r = fid >> 3, c4 = (fid & 7) * 4;
            float4 a = *(const float4*)&A0[(size_t)(i0 + r) * NN + kc + c4];
            As[c4 + 0][r] = a.x; As[c4 + 1][r] = a.y;
            As[c4 + 2][r] = a.z; As[c4 + 3][r] = a.w;
            float4 g = *(const float4*)&G0T[(size_t)(n0 + r) * NN + kc + c4];
            Bs[c4 + 0][r] = g.x; Bs[c4 + 1][r] = g.y;
            Bs[c4 + 2][r] = g.z; Bs[c4 + 3][r] = g.w;
        }
        __syncthreads();
#pragma unroll
        for (int kk = 0; kk < 32; ++kk) {
            float4 av = *(const float4*)&As[kk][ty * 4];
            float4 bv = *(const float4*)&Bs[kk][tx * 4];
            acc[0][0] = fmaf(av.x, bv.x, acc[0][0]);
            acc[0][1] = fmaf(av.x, bv.y, acc[0][1]);
            acc[0][2] = fmaf(av.x, bv.z, acc[0][2]);
            acc[0][3] = fmaf(av.x, bv.w, acc[0][3]);
            acc[1][0] = fmaf(av.y, bv.x, acc[1][0]);
            acc[1][1] = fmaf(av.y, bv.y, acc[1][1]);
            acc[1][2] = fmaf(av.y, bv.z, acc[1][2]);
            acc[1][3] = fmaf(av.y, bv.w, acc[1][3]);
            acc[2][0] = fmaf(av.z, bv.x, acc[2][0]);
            acc[2][1] = fmaf(av.z, bv.y, acc[2][1]);
            acc[2][2] = fmaf(av.z, bv.z, acc[2][2]);
            acc[2][3] = fmaf(av.z, bv.w, acc[2][3]);
            acc[3][0] = fmaf(av.w, bv.x, acc[3][0]);
            acc[3][1] = fmaf(av.w, bv.y, acc[3][1]);
            acc[3][2] = fmaf(av.w, bv.z, acc[3][2]);
            acc[3][3] = fmaf(av.w, bv.w, acc[3][3]);
        }
        __syncthreads();
    }
    int col = n0 + tx * 4;
#pragma unroll
    for (int iy = 0; iy < 4; ++iy) {
        int i = i0 + ty * 4 + iy;
        float4 o;
        o.x = acc[iy][0]; o.y = acc[iy][1]; o.z = acc[iy][2]; o.w = acc[iy][3];
        *(float4*)&P[(size_t)i * 640 + col] = o;
    }
}

// ---------------------------------------------------------------------------
// Finish layer 1 in place: X1[i][c] = relu(dis[i]*(P1a+P1b0+P1b1+G0T[c][i])+bg1)
// P1a aliases X1.
__global__ __launch_bounds__(256) void k_fin1(float* __restrict__ P1a,
                                              const float* __restrict__ P1b,
                                              const float* __restrict__ G0T,
                                              const float* __restrict__ dis,
                                              const float* __restrict__ bg1) {
    int f4 = blockIdx.x * 256 + threadIdx.x;  // < 163840
    int i = f4 / 160;
    int c4 = (f4 % 160) * 4;
    float4 a = ((const float4*)P1a)[f4];
    float4 b = ((const float4*)P1b)[f4];
    float4 c = ((const float4*)P1b)[f4 + NN * 160];
    float g0 = G0T[(size_t)(c4 + 0) * NN + i];
    float g1 = G0T[(size_t)(c4 + 1) * NN + i];
    float g2 = G0T[(size_t)(c4 + 2) * NN + i];
    float g3 = G0T[(size_t)(c4 + 3) * NN + i];
    int h0 = c4 % 40;
    float4 bv = *(const float4*)&bg1[h0];
    float di = dis[i];
    float4 o;
    o.x = fmaxf(di * (a.x + b.x + c.x + g0) + bv.x, 0.f);
    o.y = fmaxf(di * (a.y + b.y + c.y + g1) + bv.y, 0.f);
    o.z = fmaxf(di * (a.z + b.z + c.z + g2) + bv.z, 0.f);
    o.w = fmaxf(di * (a.w + b.w + c.w + g3) + bv.w, 0.f);
    ((float4*)P1a)[f4] = o;  // X1 in place
}

// ---------------------------------------------------------------------------
// G1[i][b][m] = dis[i] * sum_h X1[i][b][h] * Wg2[h][m]
__global__ __launch_bounds__(256) void k_x1w2(const float* __restrict__ X1,
                                              const float* __restrict__ Wg2,
                                              const float* __restrict__ dis,
                                              float* __restrict__ G1) {
    __shared__ float w2[NH1 * NH2];
    int tid = threadIdx.x;
    for (int idx = tid; idx < NH1 * NH2; idx += 256) w2[idx] = Wg2[idx];
    __syncthreads();
    int t = blockIdx.x * 256 + tid;  // < 16384
    int i = t >> 4, b = t & 15;
    const float* xr = X1 + (size_t)i * 640 + b * 40;
    float di = dis[i];
    float o[10];
#pragma unroll
    for (int m = 0; m < 10; ++m) o[m] = 0.f;
#pragma unroll
    for (int h4 = 0; h4 < 10; ++h4) {
        float4 xv = *(const float4*)&xr[h4 * 4];
#pragma unroll
        for (int m = 0; m < 10; ++m) {
            o[m] = fmaf(xv.x, w2[(h4 * 4 + 0) * 10 + m], o[m]);
            o[m] = fmaf(xv.y, w2[(h4 * 4 + 1) * 10 + m], o[m]);
            o[m] = fmaf(xv.z, w2[(h4 * 4 + 2) * 10 + m], o[m]);
            o[m] = fmaf(xv.w, w2[(h4 * 4 + 3) * 10 + m], o[m]);
        }
    }
    float* dst = G1 + (size_t)i * 160 + b * 10;
#pragma unroll
    for (int m = 0; m < 10; ++m) dst[m] = di * o[m];
}

// ---------------------------------------------------------------------------
// P2[kc][i][c] = sum_{j in chunk kc} A0[i,j] * G1[j][c]   (c = b*10+m, 160)
// K-split x8 for parallelism; tile 64i x 160c, micro 4x10.
__global__ __launch_bounds__(256) void k_prop2(const float* __restrict__ A0,
                                               const float* __restrict__ G1,
                                               float* __restrict__ P2) {
    __shared__ float As[32][68];
    __shared__ float Gs[32][164];
    int tid = threadIdx.x;
    int kb = blockIdx.x * 128;
    int i0 = blockIdx.y * 64;
    int cg = tid & 15, ig = tid >> 4;
    float acc[4][10] = {};
    for (int kc = 0; kc < 128; kc += 32) {
#pragma unroll
        for (int v = 0; v < 2; ++v) {
            int fid = tid + v * 256;
            int r = fid >> 3, c4 = (fid & 7) * 4;
            float4 a = *(const float4*)&A0[(size_t)(i0 + r) * NN + kb + kc + c4];
            As[c4 + 0][r] = a.x; As[c4 + 1][r] = a.y;
            As[c4 + 2][r] = a.z; As[c4 + 3][r] = a.w;
        }
#pragma unroll
        for (int v = 0; v < 5; ++v) {
            int fid = tid + v * 256;  // < 1280
            int r = fid / 40, c4 = (fid % 40) * 4;
            *(float4*)&Gs[r][c4] =
                *(const float4*)&G1[(size_t)(kb + kc + r) * 160 + c4];
        }
        __syncthreads();
#pragma unroll
        for (int kk = 0; kk < 32; ++kk) {
            float4 av = *(const float4*)&As[kk][ig * 4];
#pragma unroll
            for (int u = 0; u < 10; ++u) {
                float g = Gs[kk][cg + 16 * u];
                acc[0][u] = fmaf(av.x, g, acc[0][u]);
                acc[1][u] = fmaf(av.y, g, acc[1][u]);
                acc[2][u] = fmaf(av.z, g, acc[2][u]);
                acc[3][u] = fmaf(av.w, g, acc[3][u]);
            }
        }
        __syncthreads();
    }
#pragma unroll
    for (int iy = 0; iy < 4; ++iy) {
        float* dst = P2 + ((size_t)blockIdx.x * NN + i0 + ig * 4 + iy) * 160;
#pragma unroll
        for (int u = 0; u < 10; ++u) dst[cg + 16 * u] = acc[iy][u];
    }
}

// ---------------------------------------------------------------------------
// Reduce P2, finish layer 2, fuse X2 @ Wg3:  G2[i][b] = dis[i]*sum_m X2*Wg3
__global__ __launch_bounds__(256) void k_red2(const float* __restrict__ P2,
                                              const float* __restrict__ G1,
                                              const float* __restrict__ dis,
                                              const float* __restrict__ bg2,
                                              const float* __restrict__ Wg3,
                                              float* __restrict__ G2) {
    int t = blockIdx.x * 256 + threadIdx.x;  // < 16384
    int i = t >> 4, b = t & 15;
    float s[10];
#pragma unroll
    for (int m = 0; m < 10; ++m) s[m] = G1[(size_t)i * 160 + b * 10 + m];
    for (int kc = 0; kc < 8; ++kc) {
        const float* p = P2 + (size_t)kc * NN * 160 + (size_t)i * 160 + b * 10;
#pragma unroll
        for (int m = 0; m < 10; ++m) s[m] += p[m];
    }
    float di = dis[i];
    float g2 = 0.f;
#pragma unroll
    for (int m = 0; m < 10; ++m) {
        float x2 = fmaxf(di * s[m] + bg2[m], 0.f);
        g2 = fmaf(x2, Wg3[m], g2);
    }
    G2[(size_t)i * 16 + b] = di * g2;
}

// ---------------------------------------------------------------------------
// P3[kc][i][b] = sum_{j in chunk} A0[i,j]*G2[j][b];  tile 128i x 16b, K-split x8
__global__ __launch_bounds__(256) void k_prop3(const float* __restrict__ A0,
                                               const float* __restrict__ G2,
                                               float* __restrict__ P3) {
    __shared__ float As[32][132];
    __shared__ float G2s[128][16];
    int tid = threadIdx.x;
    int kb = blockIdx.x * 128;
    int i0 = blockIdx.y * 128;
#pragma unroll
    for (int v = 0; v < 2; ++v) {
        int fid = tid + v * 256;  // < 512
        int r = fid >> 2, c4 = (fid & 3) * 4;
        *(float4*)&G2s[r][c4] = *(const float4*)&G2[(size_t)(kb + r) * 16 + c4];
    }
    int il = tid >> 1, c0 = (tid & 1) * 8;
    float acc[8] = {};
    for (int jc = 0; jc < 128; jc += 32) {
#pragma unroll
        for (int v = 0; v < 4; ++v) {
            int fid = tid + v * 256;  // < 1024
            int r = fid >> 3, c4 = (fid & 7) * 4;
            float4 a = *(const float4*)&A0[(size_t)(i0 + r) * NN + kb + jc + c4];
            As[c4 + 0][r] = a.x; As[c4 + 1][r] = a.y;
            As[c4 + 2][r] = a.z; As[c4 + 3][r] = a.w;
        }
        __syncthreads();
#pragma unroll
        for (int kk = 0; kk < 32; ++kk) {
            float a = As[kk][il];
            float4 g0 = *(const float4*)&G2s[jc + kk][c0];
            float4 g1 = *(const float4*)&G2s[jc + kk][c0 + 4];
            acc[0] = fmaf(a, g0.x, acc[0]);
            acc[1] = fmaf(a, g0.y, acc[1]);
            acc[2] = fmaf(a, g0.z, acc[2]);
            acc[3] = fmaf(a, g0.w, acc[3]);
            acc[4] = fmaf(a, g1.x, acc[4]);
            acc[5] = fmaf(a, g1.y, acc[5]);
            acc[6] = fmaf(a, g1.z, acc[6]);
            acc[7] = fmaf(a, g1.w, acc[7]);
        }
        __syncthreads();
    }
    float* dst = P3 + (size_t)blockIdx.x * NN * 16 + (size_t)(i0 + il) * 16 + c0;
#pragma unroll
    for (int u = 0; u < 8; ++u) dst[u] = acc[u];
}

// ---------------------------------------------------------------------------
// out[b][i] = dis[i]*(sum_kc P3 + G2[i][b]) + bg3
__global__ __launch_bounds__(256) void k_red3(const float* __restrict__ P3,
                                              const float* __restrict__ G2,
                                              const float* __restrict__ dis,
                                              const float* __restrict__ bg3,
                                              float* __restrict__ out) {
    int t = blockIdx.x * 256 + threadIdx.x;  // < 16384
    int i = t >> 4, b = t & 15;
    float s = G2[(size_t)i * 16 + b];
#pragma unroll
    for (int kc = 0; kc < 8; ++kc) s += P3[(size_t)kc * NN * 16 + i * 16 + b];
    out[(size_t)b * NN + i] = dis[i] * s + bg3[0];
}

// ---------------------------------------------------------------------------
extern "C" void kernel_launch(void* const* d_in, const int* in_sizes, int n_in,
                              void* d_out, int out_size, void* d_ws,
                              size_t ws_size, hipStream_t stream) {
    (void)in_sizes; (void)n_in; (void)out_size; (void)ws_size;
    const float* x   = (const float*)d_in[0];
    const float* A   = (const float*)d_in[1];  // batch-tiled; use batch 0 only
    const float* W1  = (const float*)d_in[2];
    const float* b1  = (const float*)d_in[3];
    const float* W2  = (const float*)d_in[4];
    const float* b2  = (const float*)d_in[5];
    const float* W3  = (const float*)d_in[6];
    const float* b3  = (const float*)d_in[7];
    const float* Wg1 = (const float*)d_in[8];
    const float* bg1 = (const float*)d_in[9];
    const float* Wg2 = (const float*)d_in[10];
    const float* bg2 = (const float*)d_in[11];
    const float* Wg3 = (const float*)d_in[12];
    const float* bg3 = (const float*)d_in[13];
    float* ws  = (float*)d_ws;
    float* dis = ws + OFF_DIS;
    float* G0T = ws + OFF_G0T;
    float* X1  = ws + OFF_X1;   // also P1a (K-split partial z=0)
    float* G1  = ws + OFF_G1;
    float* G2  = ws + OFF_G2;
    float* SCR = ws + OFF_SCR;  // Pf -> P1b -> P2 -> P3 (time-shared)
    float* out = (float*)d_out;

    k_dis<<<NN, 256, 0, stream>>>(A, dis);
    k_feat<<<dim3(16, 16, 3), 256, 0, stream>>>(x, W1, b1, W2, b2, W3, b3, Wg1, SCR);
    k_combine<<<640, 256, 0, stream>>>(SCR, dis, G0T);
    k_prop1s<<<dim3(10, 16, 3), 256, 0, stream>>>(A, G0T, X1, SCR);
    k_fin1<<<640, 256, 0, stream>>>(X1, SCR, G0T, dis, bg1);
    k_x1w2<<<64, 256, 0, stream>>>(X1, Wg2, dis, G1);
    k_prop2<<<dim3(8, 16), 256, 0, stream>>>(A, G1, SCR);
    k_red2<<<64, 256, 0, stream>>>(SCR, G1, dis, bg2, Wg3, G2);
    k_prop3<<<dim3(8, 8), 256, 0, stream>>>(A, G2, SCR);
    k_red3<<<64, 256, 0, stream>>>(SCR, G2, dis, bg3, out);
}